// Round 12
// baseline (273.076 us; speedup 1.0000x reference)
//
#include <hip/hip_runtime.h>
#include <hip/hip_bf16.h>
#include <string.h>

typedef __attribute__((ext_vector_type(8))) short short8;
typedef __attribute__((ext_vector_type(4))) float floatx4;

// B=32, T=2048, D=512, U=512, M = B*T = 65536

__device__ inline uint packbf2(float lo, float hi) {
    __hip_bfloat162 h = __float22bfloat162_rn(make_float2(lo, hi));
    uint r; memcpy(&r, &h, 4); return r;
}

__device__ inline float tanh_fast(float x) {
    x = fminf(15.f, fmaxf(-15.f, x));
    float e = __expf(2.f * x);
    return __fdividef(e - 1.f, e + 1.f);
}

// ---- kernel 0: fused prep (proven, rounds 5/7/8/10/11).
// blocks 0..127:   pack W1_enc -> bf16 MFMA B-frag chunks (Wp)
// blocks 128..383: dec[b][u] = h_dec[b]·W1_dec[:,u] + b1[u]
// blocks 384..447: zero ctx (for kctx3 atomicAdd)
__global__ void kprep(const float* __restrict__ W1, const float* __restrict__ hdec,
                      const float* __restrict__ b1, ushort* __restrict__ Wp,
                      float* __restrict__ dec, float* __restrict__ ctx) {
    __shared__ float red[4][64];
    int tid = threadIdx.x;
    if (blockIdx.x < 128) {
        int wid = blockIdx.x * 4 + (tid >> 6);       // 0..511 chunks
        int l = tid & 63;
        int kc = wid >> 5, ng = wid & 31;
        int m = l & 15, g = l >> 4;
        const float* src = W1 + (size_t)(kc * 32 + g * 8) * 512 + ng * 16 + m;
        uint u4[4];
        #pragma unroll
        for (int e = 0; e < 4; ++e)
            u4[e] = packbf2(src[(size_t)(2 * e) * 512], src[(size_t)(2 * e + 1) * 512]);
        *(uint4*)(Wp + (size_t)wid * 512 + l * 8) = *(uint4*)u4;
    } else if (blockIdx.x < 384) {
        int bid = blockIdx.x - 128;                  // 0..255
        int b = bid >> 3, ug = bid & 7;
        int u = ug * 64 + (tid & 63), dq = tid >> 6;
        const float* hb = hdec + b * 512 + dq * 128;
        const float* w = W1 + (size_t)(512 + dq * 128) * 512 + u;
        float a = 0.f;
        #pragma unroll 8
        for (int d = 0; d < 128; ++d)
            a += hb[d] * w[(size_t)d * 512];
        red[dq][tid & 63] = a;
        __syncthreads();
        if (tid < 64)
            dec[b * 512 + ug * 64 + tid] =
                red[0][tid] + red[1][tid] + red[2][tid] + red[3][tid] + b1[ug * 64 + tid];
    } else {
        ctx[(blockIdx.x - 384) * 256 + tid] = 0.f;   // 64 blocks x 256 = 16384
    }
}

// ---- kernel 1: fused GEMM + tanh + dot(W2) -> e2 (round-0 body, FROZEN —
// best measured: 89-94 µs, VGPR 60, 0 bank conflicts, no spill).
__global__ __launch_bounds__(512, 4) void kgemm(
        const float* __restrict__ A, const ushort* __restrict__ Wp,
        const float* __restrict__ dec, const float* __restrict__ W2,
        float* __restrict__ e2) {
    __shared__ __align__(16) ushort As[32768];   // 64 KB
    __shared__ float red[8][64];                 // 2 KB
    const int tid = threadIdx.x;
    const int rowbase = blockIdx.x * 64;
    const int bIdx = blockIdx.x >> 5;            // 32 blocks per batch

    // stage A tile: 64 rows x 512 k, fp32 -> bf16, fragment-chunk order
    #pragma unroll
    for (int p = 0; p < 8; ++p) {
        int s = tid + 512 * p;                   // 0..4095 lane-slots
        int chunk = s >> 6, l = s & 63;
        int i = chunk >> 4, kc = chunk & 15;
        int m = l & 15, gg = l >> 4;
        const float* gp = A + (size_t)(rowbase + i * 16 + m) * 512 + kc * 32 + gg * 8;
        float4 f0 = *(const float4*)gp;
        float4 f1 = *(const float4*)(gp + 4);
        uint4 u;
        u.x = packbf2(f0.x, f0.y); u.y = packbf2(f0.z, f0.w);
        u.z = packbf2(f1.x, f1.y); u.w = packbf2(f1.z, f1.w);
        *(uint4*)&As[chunk * 512 + l * 8] = u;
    }
    __syncthreads();

    const int lane = tid & 63, wave = tid >> 6;
    const int c = lane & 15, g = lane >> 4;

    floatx4 acc[4][4];
    #pragma unroll
    for (int i = 0; i < 4; i++)
        #pragma unroll
        for (int j = 0; j < 4; j++) acc[i][j] = (floatx4){0.f, 0.f, 0.f, 0.f};

    const int ng0 = wave * 4;                    // wave covers cols wave*64..+63
    #pragma unroll 2
    for (int kc = 0; kc < 16; ++kc) {
        short8 bfr[4];
        #pragma unroll
        for (int j = 0; j < 4; ++j)
            bfr[j] = *(const short8*)&Wp[(size_t)(kc * 32 + ng0 + j) * 512 + lane * 8];
        short8 afr[4];
        #pragma unroll
        for (int i = 0; i < 4; ++i)
            afr[i] = *(const short8*)&As[(i * 16 + kc) * 512 + lane * 8];
        #pragma unroll
        for (int j = 0; j < 4; ++j)
            #pragma unroll
            for (int i = 0; i < 4; ++i)
                acc[i][j] = __builtin_amdgcn_mfma_f32_16x16x32_bf16(afr[i], bfr[j], acc[i][j], 0, 0, 0);
    }

    // epilogue: z += dec; p = sum_u tanh(z)*W2[u]; reduce 16 lanes + 8 waves
    float w2v[4], dv[4];
    #pragma unroll
    for (int j = 0; j < 4; j++) {
        int n = wave * 64 + j * 16 + c;
        w2v[j] = W2[n];
        dv[j]  = dec[bIdx * 512 + n];
    }
    #pragma unroll
    for (int i = 0; i < 4; i++) {
        #pragma unroll
        for (int r = 0; r < 4; r++) {
            float p = 0.f;
            #pragma unroll
            for (int j = 0; j < 4; j++)
                p += tanh_fast(acc[i][j][r] + dv[j]) * w2v[j];
            p += __shfl_xor(p, 1, 16);
            p += __shfl_xor(p, 2, 16);
            p += __shfl_xor(p, 4, 16);
            p += __shfl_xor(p, 8, 16);
            if (c == 0) red[wave][i * 16 + g * 4 + r] = p;
        }
    }
    __syncthreads();
    if (tid < 64) {
        float s = 0.f;
        #pragma unroll
        for (int w = 0; w < 8; ++w) s += red[w][tid];
        e2[rowbase + tid] = s;
    }
}

// ---- kernel 2: per-batch softmax stats (max, 1/sum) -> sm[b] (proven R0 body)
__global__ void ksm(const float* __restrict__ e2, const float* __restrict__ b2,
                    float* __restrict__ sm) {
    int b = blockIdx.x, tid = threadIdx.x;
    int lane = tid & 63, wave = tid >> 6;
    float b2v = b2[0];
    float f[8];
    float mx = 0.f;                                  // relu values >= 0
    #pragma unroll
    for (int i = 0; i < 8; i++) {
        f[i] = fmaxf(e2[b * 2048 + i * 256 + tid] + b2v, 0.f);
        mx = fmaxf(mx, f[i]);
    }
    #pragma unroll
    for (int off = 1; off < 64; off <<= 1) mx = fmaxf(mx, __shfl_xor(mx, off));
    __shared__ float red[4], red2[4];
    if (lane == 0) red[wave] = mx;
    __syncthreads();
    mx = fmaxf(fmaxf(red[0], red[1]), fmaxf(red[2], red[3]));
    float s = 0.f;
    #pragma unroll
    for (int i = 0; i < 8; i++) s += __expf(f[i] - mx);
    #pragma unroll
    for (int off = 1; off < 64; off <<= 1) s += __shfl_xor(s, off);
    if (lane == 0) red2[wave] = s;
    __syncthreads();
    if (tid == 0) {
        float ss = red2[0] + red2[1] + red2[2] + red2[3];
        sm[b * 2 + 0] = mx;
        sm[b * 2 + 1] = 1.f / ss;
    }
}

// ---- kernel 3: lean streaming context. Block (b,ch): read (mx,inv), compute
// own 64 attn values directly, then dual-stream weighted sum of h_enc rows
// (2 independent 8-row streams per thread -> 2x loads in flight).
__global__ __launch_bounds__(512) void kctx3(const float* __restrict__ A,
        const float* __restrict__ e2, const float* __restrict__ b2,
        const float* __restrict__ sm, float* __restrict__ attn,
        float* __restrict__ ctx) {
    __shared__ float at[64];
    __shared__ float4 red[3][128];
    int b = blockIdx.x, ch = blockIdx.y, tid = threadIdx.x;
    float mx = sm[b * 2 + 0], inv = sm[b * 2 + 1];
    float b2v = b2[0];

    if (tid < 64) {
        float z = fmaxf(e2[b * 2048 + ch * 64 + tid] + b2v, 0.f);
        float a = __expf(z - mx) * inv;
        at[tid] = a;
        attn[b * 2048 + ch * 64 + tid] = a;
    }
    __syncthreads();

    int dt = tid & 127, th = tid >> 7;               // th in 0..3
    // stream 0: rows ch*64 + th*8 + tt; stream 1: rows ch*64 + 32 + th*8 + tt
    const float* base0 = A + ((size_t)b * 2048 + ch * 64 + th * 8) * 512 + dt * 4;
    const float* base1 = base0 + (size_t)32 * 512;
    const float* aw0 = at + th * 8;
    const float* aw1 = at + 32 + th * 8;
    float4 acc0 = (float4){0.f, 0.f, 0.f, 0.f};
    float4 acc1 = (float4){0.f, 0.f, 0.f, 0.f};
    #pragma unroll
    for (int tt = 0; tt < 8; ++tt) {
        float a0 = aw0[tt], a1 = aw1[tt];
        float4 h0 = *(const float4*)(base0 + (size_t)tt * 512);
        float4 h1 = *(const float4*)(base1 + (size_t)tt * 512);
        acc0.x += a0 * h0.x; acc0.y += a0 * h0.y;
        acc0.z += a0 * h0.z; acc0.w += a0 * h0.w;
        acc1.x += a1 * h1.x; acc1.y += a1 * h1.y;
        acc1.z += a1 * h1.z; acc1.w += a1 * h1.w;
    }
    float4 acc;
    acc.x = acc0.x + acc1.x; acc.y = acc0.y + acc1.y;
    acc.z = acc0.z + acc1.z; acc.w = acc0.w + acc1.w;
    if (th) red[th - 1][dt] = acc;
    __syncthreads();
    if (th == 0) {
        float4 o0 = red[0][dt], o1 = red[1][dt], o2 = red[2][dt];
        float* cp = ctx + (size_t)b * 512 + dt * 4;
        atomicAdd(cp + 0, acc.x + o0.x + o1.x + o2.x);
        atomicAdd(cp + 1, acc.y + o0.y + o1.y + o2.y);
        atomicAdd(cp + 2, acc.z + o0.z + o1.z + o2.z);
        atomicAdd(cp + 3, acc.w + o0.w + o1.w + o2.w);
    }
}

extern "C" void kernel_launch(void* const* d_in, const int* in_sizes, int n_in,
                              void* d_out, int out_size, void* d_ws, size_t ws_size,
                              hipStream_t stream) {
    const float* h_enc = (const float*)d_in[0];
    const float* h_dec = (const float*)d_in[1];
    const float* W1    = (const float*)d_in[2];
    const float* b1    = (const float*)d_in[3];
    const float* W2    = (const float*)d_in[4];
    const float* b2    = (const float*)d_in[5];
    float* out  = (float*)d_out;
    float* ctx  = out;              // 32*512
    float* attn = out + 32 * 512;   // 32*2048

    char* ws = (char*)d_ws;
    ushort* Wp = (ushort*)ws;                          // 512 KB @ 0
    float* dec  = (float*)(ws + (512 << 10));          // 64 KB  @ 512K
    float* e2   = (float*)(ws + (576 << 10));          // 256 KB @ 576K
    float* sm   = (float*)(ws + (832 << 10));          // 256 B  @ 832K

    kprep<<<448, 256, 0, stream>>>(W1, h_dec, b1, Wp, dec, ctx);
    kgemm<<<1024, 512, 0, stream>>>(h_enc, Wp, dec, W2, e2);
    ksm<<<32, 256, 0, stream>>>(e2, b2, sm);
    dim3 g3(32, 32);
    kctx3<<<g3, 512, 0, stream>>>(h_enc, e2, b2, sm, attn, ctx);
}